// Round 2
// baseline (175078.882 us; speedup 1.0000x reference)
//
#include <hip/hip_runtime.h>
#include <hip/hip_cooperative_groups.h>
#include <math.h>

namespace cg = cooperative_groups;

// Problem constants
#define N_PTS   30000
#define DIM     64
#define K_C     500
#define K_PAD   512
#define N_ITERS 1000

// tiling
#define BM 128
#define BN 128
#define NTILE 4            // K_PAD / BN
#define GRIDSZ 235         // ceil(30000/128) blocks; <=256 -> co-resident
#define NTH 256
#define NLANES (GRIDSZ * NTH)

// fixed-point accumulation: exact int64 atomics -> deterministic
#define FPSCALE 16777216.0f          // 2^24
#define INV_FPSCALE (1.0 / 16777216.0)

struct SMem {
  float As[DIM][BM];                 // 32 KB, loop-invariant (staged once)
  union {
    float Bs[DIM][BN];               // 32 KB, restaged per tile per iter
    int blkidx[BM];                  // reused after last tile's reads
  } u;
};                                    // 64 KB total

__global__ __launch_bounds__(NTH, 1) void k_kmeans(
    const float* __restrict__ embeds, const float* __restrict__ init_c,
    float* __restrict__ out,
    float* __restrict__ cents, float* __restrict__ csq,
    float* __restrict__ esq, int* __restrict__ idx,
    float* __restrict__ cntf, int* __restrict__ gcnt,
    long long* __restrict__ gsum) {
  cg::grid_group grid = cg::this_grid();
  __shared__ SMem sm;
  const int tid = threadIdx.x;
  const int b = blockIdx.x;
  const int gid = b * NTH + tid;
  const int lane = tid & 63;
  const int wid_g = gid >> 6;
  const int nw = NLANES / 64;

  // ---------------- phase 0: init (once) ----------------
  for (int i = gid; i < K_C * DIM; i += NLANES) { gsum[i] = 0; cents[i] = init_c[i]; }
  for (int i = gid; i < K_C; i += NLANES) gcnt[i] = 0;
  for (int p = wid_g; p < N_PTS; p += nw) {
    float v = embeds[(size_t)p * DIM + lane];
    float s = v * v;
    #pragma unroll
    for (int m = 1; m < 64; m <<= 1) s += __shfl_xor(s, m, 64);
    if (lane == 0) esq[p] = s;
  }
  for (int k = wid_g; k < K_PAD; k += nw) {
    float v = (k < K_C) ? init_c[(size_t)k * DIM + lane] : 0.f;
    float s = v * v;
    #pragma unroll
    for (int m = 1; m < 64; m <<= 1) s += __shfl_xor(s, m, 64);
    if (lane == 0) csq[k] = (k < K_C) ? s : INFINITY;
  }
  __threadfence();
  grid.sync();

  // ---------------- loop-invariant per-block state ----------------
  const int m0 = b * BM;
  const int m_cnt = min(BM, N_PTS - m0);
  const int tx = tid & 15, ty = tid >> 4;

  // stage A once (transposed): As[d][m]
  #pragma unroll
  for (int l = 0; l < 8; ++l) {
    int e = tid + l * 256;
    int pl = e >> 4, d4 = e & 15;
    int p = m0 + pl;
    float4 v = make_float4(0.f, 0.f, 0.f, 0.f);
    if (p < N_PTS) v = *reinterpret_cast<const float4*>(embeds + (size_t)p * DIM + d4 * 4);
    sm.As[d4 * 4 + 0][pl] = v.x; sm.As[d4 * 4 + 1][pl] = v.y;
    sm.As[d4 * 4 + 2][pl] = v.z; sm.As[d4 * 4 + 3][pl] = v.w;
  }
  float esq_r[8];
  #pragma unroll
  for (int i = 0; i < 8; ++i) {
    int p = m0 + ty * 8 + i;
    esq_r[i] = (p < N_PTS) ? esq[p] : 0.f;
  }
  // no extra barrier needed: first grid-interaction below is after __syncthreads in tile loop

  const int g_acc = tid >> 6;        // 4 groups of 64 lanes for accumulation

  for (int it = 0; it < N_ITERS; ++it) {
    float best[8]; int bidx[8];
    #pragma unroll
    for (int i = 0; i < 8; ++i) { best[i] = INFINITY; bidx[i] = 0; }

    for (int t = 0; t < NTILE; ++t) {
      const int n0 = t * BN;
      __syncthreads();               // protect previous Bs readers (and As staging at it=0,t=0)
      #pragma unroll
      for (int l = 0; l < 8; ++l) {
        int e2 = tid + l * 256;
        int kl = e2 >> 4, d4 = e2 & 15;
        int k = n0 + kl;
        float4 v = make_float4(0.f, 0.f, 0.f, 0.f);
        if (k < K_C) v = *reinterpret_cast<const float4*>(cents + (size_t)k * DIM + d4 * 4);
        sm.u.Bs[d4 * 4 + 0][kl] = v.x; sm.u.Bs[d4 * 4 + 1][kl] = v.y;
        sm.u.Bs[d4 * 4 + 2][kl] = v.z; sm.u.Bs[d4 * 4 + 3][kl] = v.w;
      }
      __syncthreads();

      float acc[8][8];
      #pragma unroll
      for (int i = 0; i < 8; ++i)
        #pragma unroll
        for (int j = 0; j < 8; ++j) acc[i][j] = 0.f;

      #pragma unroll 8
      for (int d = 0; d < DIM; ++d) {
        float4 a0 = *reinterpret_cast<const float4*>(&sm.As[d][ty * 8]);
        float4 a1 = *reinterpret_cast<const float4*>(&sm.As[d][ty * 8 + 4]);
        float4 b0 = *reinterpret_cast<const float4*>(&sm.u.Bs[d][tx * 8]);
        float4 b1 = *reinterpret_cast<const float4*>(&sm.u.Bs[d][tx * 8 + 4]);
        float av[8] = {a0.x, a0.y, a0.z, a0.w, a1.x, a1.y, a1.z, a1.w};
        float bv[8] = {b0.x, b0.y, b0.z, b0.w, b1.x, b1.y, b1.z, b1.w};
        #pragma unroll
        for (int i = 0; i < 8; ++i)
          #pragma unroll
          for (int j = 0; j < 8; ++j)
            acc[i][j] = fmaf(av[i], bv[j], acc[i][j]);
      }

      float4 c0 = *reinterpret_cast<const float4*>(&csq[n0 + tx * 8]);
      float4 c1 = *reinterpret_cast<const float4*>(&csq[n0 + tx * 8 + 4]);
      float cv[8] = {c0.x, c0.y, c0.z, c0.w, c1.x, c1.y, c1.z, c1.w};
      #pragma unroll
      for (int j = 0; j < 8; ++j) {
        int n = n0 + tx * 8 + j;
        #pragma unroll
        for (int i = 0; i < 8; ++i) {
          float dd = (esq_r[i] - 2.0f * acc[i][j]) + cv[j];
          if (dd < best[i]) { best[i] = dd; bidx[i] = n; }
        }
      }
    }

    // cross-lane argmin over 16 tx lanes (registers only)
    #pragma unroll
    for (int i = 0; i < 8; ++i) {
      float v = best[i]; int bi = bidx[i];
      #pragma unroll
      for (int s = 1; s < 16; s <<= 1) {
        float ov = __shfl_xor(v, s, 64);
        int   oi = __shfl_xor(bi, s, 64);
        if (ov < v || (ov == v && oi < bi)) { v = ov; bi = oi; }
      }
      best[i] = v; bidx[i] = bi;
    }

    __syncthreads();                 // all Bs reads done before aliasing with blkidx
    if (tx == 0) {
      #pragma unroll
      for (int i = 0; i < 8; ++i) {
        int pl = ty * 8 + i;
        sm.u.blkidx[pl] = bidx[i];
        int p = m0 + pl;
        if (p < N_PTS) idx[p] = bidx[i];
      }
    }
    __syncthreads();

    // fused accumulation: int64 fixed-point atomics (exact, deterministic)
    for (int pl = g_acc; pl < m_cnt; pl += 4) {
      int k = sm.u.blkidx[pl];
      float v = embeds[(size_t)(m0 + pl) * DIM + lane];
      long long iv = __float2ll_rn(v * FPSCALE);
      atomicAdd((unsigned long long*)&gsum[k * DIM + lane], (unsigned long long)iv);
      if (lane == 0) atomicAdd(&gcnt[k], 1);
    }
    __threadfence();
    grid.sync();

    // update phase: 32000 elems over first 125 blocks (wave-aligned cutoff)
    if (gid < K_C * DIM) {
      int k = gid >> 6;
      long long s = gsum[gid];
      int c = gcnt[k];
      float sum_f = (float)((double)s * INV_FPSCALE);
      float nc = sum_f / ((float)c + 1e-6f);   // matches sums / (counts + EPS)
      cents[gid] = nc;
      float sq = nc * nc;
      #pragma unroll
      for (int m = 1; m < 64; m <<= 1) sq += __shfl_xor(sq, m, 64);
      gsum[gid] = 0;                           // re-zero for next iteration
      if (lane == 0) { csq[k] = sq; cntf[k] = (float)c; gcnt[k] = 0; }
    }
    __threadfence();
    grid.sync();
  }

  // ---------------- final output ----------------
  const int tot = K_C * DIM + N_PTS + K_C;
  for (int i = gid; i < tot; i += NLANES) {
    float v;
    if (i < K_C * DIM) v = cents[i];
    else if (i < K_C * DIM + N_PTS) v = (float)idx[i - K_C * DIM];
    else v = cntf[i - K_C * DIM - N_PTS];
    out[i] = v;
  }
}

// ---------------------------------------------------------------------------
extern "C" void kernel_launch(void* const* d_in, const int* in_sizes, int n_in,
                              void* d_out, int out_size, void* d_ws, size_t ws_size,
                              hipStream_t stream) {
  const float* embeds = (const float*)d_in[0];
  const float* init_c = (const float*)d_in[1];
  float* out = (float*)d_out;

  char* w = (char*)d_ws;
  size_t off = 0;
  auto alloc = [&](size_t bytes) -> void* {
    void* p = w + off;
    off += (bytes + 255) & ~(size_t)255;
    return p;
  };
  float*     cents = (float*)    alloc((size_t)K_C * DIM * sizeof(float));
  float*     csq   = (float*)    alloc((size_t)K_PAD * sizeof(float));
  float*     esq   = (float*)    alloc((size_t)N_PTS * sizeof(float));
  int*       idx   = (int*)      alloc((size_t)N_PTS * sizeof(int));
  float*     cntf  = (float*)    alloc((size_t)K_C * sizeof(float));
  int*       gcnt  = (int*)      alloc((size_t)K_C * sizeof(int));
  long long* gsum  = (long long*)alloc((size_t)K_C * DIM * sizeof(long long));

  void* args[] = {(void*)&embeds, (void*)&init_c, (void*)&out,
                  (void*)&cents, (void*)&csq, (void*)&esq, (void*)&idx,
                  (void*)&cntf, (void*)&gcnt, (void*)&gsum};
  hipLaunchCooperativeKernel((void*)k_kmeans, dim3(GRIDSZ), dim3(NTH), args, 0, stream);
}

// Round 3
// 160102.966 us; speedup vs baseline: 1.0935x; 1.0935x over previous
//
#include <hip/hip_runtime.h>
#include <hip/hip_cooperative_groups.h>
#include <math.h>

namespace cg = cooperative_groups;

// Problem constants
#define N_PTS   30000
#define DIM     64
#define K_C     500
#define K_PAD   512
#define N_ITERS 1000

// tiling
#define BM 128
#define BN 128
#define NTILE 4            // K_PAD / BN
#define GRIDSZ 235         // ceil(30000/128) blocks; <=256 -> co-resident
#define NTH 256
#define NLANES (GRIDSZ * NTH)

#define NREP 8             // atomic-contention replicas

// fixed-point accumulation: exact int64 atomics -> deterministic
#define FPSCALE 16777216.0f          // 2^24
#define INV_FPSCALE (1.0 / 16777216.0)

struct SMem {
  float As[DIM][BM];                 // 32 KB, loop-invariant (staged once)
  union {
    float Bs[DIM][BN];               // 32 KB, restaged per tile per iter
    int blkidx[BM];                  // reused after last tile's reads
  } u;
};                                    // 64 KB total

__global__ __launch_bounds__(NTH, 1) void k_kmeans(
    const float* __restrict__ embeds, const float* __restrict__ init_c,
    float* __restrict__ out,
    float* __restrict__ cents, float* __restrict__ csq,
    float* __restrict__ esq, int* __restrict__ idx,
    float* __restrict__ cntf, int* __restrict__ gcnt,
    long long* __restrict__ gsum) {
  cg::grid_group grid = cg::this_grid();
  __shared__ SMem sm;
  const int tid = threadIdx.x;
  const int b = blockIdx.x;
  const int gid = b * NTH + tid;
  const int lane = tid & 63;
  const int wid_g = gid >> 6;
  const int nw = NLANES / 64;
  const int rep = b & (NREP - 1);

  // ---------------- phase 0: init (once) ----------------
  for (int i = gid; i < NREP * K_C * DIM; i += NLANES) gsum[i] = 0;
  for (int i = gid; i < K_C * DIM; i += NLANES) cents[i] = init_c[i];
  for (int i = gid; i < NREP * K_C; i += NLANES) gcnt[i] = 0;
  for (int p = wid_g; p < N_PTS; p += nw) {
    float v = embeds[(size_t)p * DIM + lane];
    float s = v * v;
    #pragma unroll
    for (int m = 1; m < 64; m <<= 1) s += __shfl_xor(s, m, 64);
    if (lane == 0) esq[p] = s;
  }
  for (int k = wid_g; k < K_PAD; k += nw) {
    float v = (k < K_C) ? init_c[(size_t)k * DIM + lane] : 0.f;
    float s = v * v;
    #pragma unroll
    for (int m = 1; m < 64; m <<= 1) s += __shfl_xor(s, m, 64);
    if (lane == 0) csq[k] = (k < K_C) ? s : INFINITY;
  }
  __threadfence();
  grid.sync();

  // ---------------- loop-invariant per-block state ----------------
  const int m0 = b * BM;
  const int m_cnt = min(BM, N_PTS - m0);
  const int tx = tid & 15, ty = tid >> 4;

  // stage A once (transposed): As[d][m]  (one-time; conflicts here don't matter)
  #pragma unroll
  for (int l = 0; l < 8; ++l) {
    int e = tid + l * 256;
    int pl = e >> 4, d4 = e & 15;
    int p = m0 + pl;
    float4 v = make_float4(0.f, 0.f, 0.f, 0.f);
    if (p < N_PTS) v = *reinterpret_cast<const float4*>(embeds + (size_t)p * DIM + d4 * 4);
    sm.As[d4 * 4 + 0][pl] = v.x; sm.As[d4 * 4 + 1][pl] = v.y;
    sm.As[d4 * 4 + 2][pl] = v.z; sm.As[d4 * 4 + 3][pl] = v.w;
  }
  // split m-frag: rows ty*4..+3 and 64+ty*4..+3  (conflict-free b128 reads)
  float esq_r[8];
  #pragma unroll
  for (int i = 0; i < 8; ++i) {
    int mi = (i < 4) ? (ty * 4 + i) : (64 + ty * 4 + (i - 4));
    int p = m0 + mi;
    esq_r[i] = (p < N_PTS) ? esq[p] : 0.f;
  }

  const int g_acc = tid >> 6;        // 4 groups of 64 lanes for accumulation

  for (int it = 0; it < N_ITERS; ++it) {
    float best[8]; int bidx[8];
    #pragma unroll
    for (int i = 0; i < 8; ++i) { best[i] = INFINITY; bidx[i] = 0; }

    for (int t = 0; t < NTILE; ++t) {
      const int n0 = t * BN;
      __syncthreads();               // protect previous Bs/blkidx readers
      // stage B tile, lane-major in kl so scalar-write banks = kl%32 (conflict-free)
      #pragma unroll
      for (int l = 0; l < 8; ++l) {
        int e2 = tid + l * 256;
        int kl = e2 & 127, d4 = e2 >> 7;
        int k = n0 + kl;
        float4 v = make_float4(0.f, 0.f, 0.f, 0.f);
        if (k < K_C) v = *reinterpret_cast<const float4*>(cents + (size_t)k * DIM + d4 * 4);
        sm.u.Bs[d4 * 4 + 0][kl] = v.x; sm.u.Bs[d4 * 4 + 1][kl] = v.y;
        sm.u.Bs[d4 * 4 + 2][kl] = v.z; sm.u.Bs[d4 * 4 + 3][kl] = v.w;
      }
      __syncthreads();

      float acc[8][8];
      #pragma unroll
      for (int i = 0; i < 8; ++i)
        #pragma unroll
        for (int j = 0; j < 8; ++j) acc[i][j] = 0.f;

      #pragma unroll 8
      for (int d = 0; d < DIM; ++d) {
        float4 a0 = *reinterpret_cast<const float4*>(&sm.As[d][ty * 4]);
        float4 a1 = *reinterpret_cast<const float4*>(&sm.As[d][64 + ty * 4]);
        float4 b0 = *reinterpret_cast<const float4*>(&sm.u.Bs[d][tx * 4]);
        float4 b1 = *reinterpret_cast<const float4*>(&sm.u.Bs[d][64 + tx * 4]);
        float av[8] = {a0.x, a0.y, a0.z, a0.w, a1.x, a1.y, a1.z, a1.w};
        float bv[8] = {b0.x, b0.y, b0.z, b0.w, b1.x, b1.y, b1.z, b1.w};
        #pragma unroll
        for (int i = 0; i < 8; ++i)
          #pragma unroll
          for (int j = 0; j < 8; ++j)
            acc[i][j] = fmaf(av[i], bv[j], acc[i][j]);
      }

      float4 c0 = *reinterpret_cast<const float4*>(&csq[n0 + tx * 4]);
      float4 c1 = *reinterpret_cast<const float4*>(&csq[n0 + 64 + tx * 4]);
      float cv[8] = {c0.x, c0.y, c0.z, c0.w, c1.x, c1.y, c1.z, c1.w};
      #pragma unroll
      for (int j = 0; j < 8; ++j) {
        int n = n0 + ((j < 4) ? (tx * 4 + j) : (64 + tx * 4 + (j - 4)));
        #pragma unroll
        for (int i = 0; i < 8; ++i) {
          float dd = (esq_r[i] - 2.0f * acc[i][j]) + cv[j];
          if (dd < best[i]) { best[i] = dd; bidx[i] = n; }
        }
      }
    }

    // cross-lane argmin over 16 tx lanes (registers only)
    #pragma unroll
    for (int i = 0; i < 8; ++i) {
      float v = best[i]; int bi = bidx[i];
      #pragma unroll
      for (int s = 1; s < 16; s <<= 1) {
        float ov = __shfl_xor(v, s, 64);
        int   oi = __shfl_xor(bi, s, 64);
        if (ov < v || (ov == v && oi < bi)) { v = ov; bi = oi; }
      }
      best[i] = v; bidx[i] = bi;
    }

    __syncthreads();                 // all Bs reads done before aliasing with blkidx
    if (tx == 0) {
      #pragma unroll
      for (int i = 0; i < 8; ++i) {
        int pl = (i < 4) ? (ty * 4 + i) : (64 + ty * 4 + (i - 4));
        sm.u.blkidx[pl] = bidx[i];
        int p = m0 + pl;
        if (p < N_PTS) idx[p] = bidx[i];
      }
    }
    __syncthreads();

    // fused accumulation: int64 fixed-point atomics, NREP-replicated targets
    long long* gs = gsum + (size_t)rep * (K_C * DIM);
    int* gc = gcnt + rep * K_C;
    #pragma unroll 4
    for (int pl = g_acc; pl < m_cnt; pl += 4) {
      int k = sm.u.blkidx[pl];
      float v = embeds[(size_t)(m0 + pl) * DIM + lane];
      long long iv = __float2ll_rn(v * FPSCALE);
      atomicAdd((unsigned long long*)&gs[k * DIM + lane], (unsigned long long)iv);
      if (lane == 0) atomicAdd(&gc[k], 1);
    }
    __threadfence();
    grid.sync();

    // update phase: 32000 elems over first 125 blocks (wave-aligned cutoff)
    if (gid < K_C * DIM) {
      int k = gid >> 6;
      long long s = 0;
      #pragma unroll
      for (int r = 0; r < NREP; ++r) {
        s += gsum[(size_t)r * (K_C * DIM) + gid];
        gsum[(size_t)r * (K_C * DIM) + gid] = 0;   // re-zero for next iter
      }
      int c = 0;
      #pragma unroll
      for (int r = 0; r < NREP; ++r) c += gcnt[r * K_C + k];
      float sum_f = (float)((double)s * INV_FPSCALE);
      float nc = sum_f / ((float)c + 1e-6f);   // matches sums / (counts + EPS)
      cents[gid] = nc;
      float sq = nc * nc;
      #pragma unroll
      for (int m = 1; m < 64; m <<= 1) sq += __shfl_xor(sq, m, 64);
      if (lane == 0) {
        csq[k] = sq; cntf[k] = (float)c;
        #pragma unroll
        for (int r = 0; r < NREP; ++r) gcnt[r * K_C + k] = 0;
      }
    }
    __threadfence();
    grid.sync();
  }

  // ---------------- final output ----------------
  const int tot = K_C * DIM + N_PTS + K_C;
  for (int i = gid; i < tot; i += NLANES) {
    float v;
    if (i < K_C * DIM) v = cents[i];
    else if (i < K_C * DIM + N_PTS) v = (float)idx[i - K_C * DIM];
    else v = cntf[i - K_C * DIM - N_PTS];
    out[i] = v;
  }
}

// ---------------------------------------------------------------------------
extern "C" void kernel_launch(void* const* d_in, const int* in_sizes, int n_in,
                              void* d_out, int out_size, void* d_ws, size_t ws_size,
                              hipStream_t stream) {
  const float* embeds = (const float*)d_in[0];
  const float* init_c = (const float*)d_in[1];
  float* out = (float*)d_out;

  char* w = (char*)d_ws;
  size_t off = 0;
  auto alloc = [&](size_t bytes) -> void* {
    void* p = w + off;
    off += (bytes + 255) & ~(size_t)255;
    return p;
  };
  float*     cents = (float*)    alloc((size_t)K_C * DIM * sizeof(float));
  float*     csq   = (float*)    alloc((size_t)K_PAD * sizeof(float));
  float*     esq   = (float*)    alloc((size_t)N_PTS * sizeof(float));
  int*       idx   = (int*)      alloc((size_t)N_PTS * sizeof(int));
  float*     cntf  = (float*)    alloc((size_t)K_C * sizeof(float));
  int*       gcnt  = (int*)      alloc((size_t)NREP * K_C * sizeof(int));
  long long* gsum  = (long long*)alloc((size_t)NREP * K_C * DIM * sizeof(long long));

  void* args[] = {(void*)&embeds, (void*)&init_c, (void*)&out,
                  (void*)&cents, (void*)&csq, (void*)&esq, (void*)&idx,
                  (void*)&cntf, (void*)&gcnt, (void*)&gsum};
  hipLaunchCooperativeKernel((void*)k_kmeans, dim3(GRIDSZ), dim3(NTH), args, 0, stream);
}

// Round 4
// 104989.941 us; speedup vs baseline: 1.6676x; 1.5249x over previous
//
#include <hip/hip_runtime.h>
#include <math.h>

// Problem constants
#define N_PTS   30000
#define DIM     64
#define K_C     500
#define K_PAD   512
#define N_ITERS 1000

// tiling
#define BM 128
#define BN 128
#define NTILE 4            // K_PAD / BN
#define GRIDSZ 235         // ceil(30000/128) blocks; <=256 -> co-resident
#define NTH 256
#define NLANES (GRIDSZ * NTH)

#define NREP 8             // atomic-contention replicas
#define NBAR (2 * N_ITERS + 4)
#define READY_MAGIC 0x13579BDF

// fixed-point accumulation: exact int64 atomics -> deterministic
#define FPSCALE 16777216.0f          // 2^24
#define INV_FPSCALE (1.0 / 16777216.0)

struct SMem {
  float As[DIM][BM];                 // 32 KB, loop-invariant (staged once)
  union {
    float Bs[DIM][BN];               // 32 KB, restaged per tile per iter
    int blkidx[BM];                  // reused after last tile's reads
  } u;
};                                    // 64 KB total

// Minimal grid barrier: per-instance counter (never reset), release-arrive,
// relaxed spin + acquire fence. Requires all blocks co-resident (coop launch).
__device__ __forceinline__ void grid_barrier(int* cnt) {
  __syncthreads();
  if (threadIdx.x == 0) {
    __threadfence();  // release: make our plain stores device-visible (L2 wb)
    __hip_atomic_fetch_add(cnt, 1, __ATOMIC_RELEASE, __HIP_MEMORY_SCOPE_AGENT);
    while (__hip_atomic_load(cnt, __ATOMIC_RELAXED, __HIP_MEMORY_SCOPE_AGENT) < GRIDSZ)
      __builtin_amdgcn_s_sleep(1);
    __threadfence();  // acquire: invalidate so we see others' stores
  }
  __syncthreads();
}

__global__ __launch_bounds__(NTH, 1) void k_kmeans(
    const float* __restrict__ embeds, const float* __restrict__ init_c,
    float* __restrict__ out,
    float* __restrict__ cents, float* __restrict__ csq,
    float* __restrict__ esq, int* __restrict__ idx,
    float* __restrict__ cntf, int* __restrict__ gcnt,
    long long* __restrict__ gsum, int* __restrict__ barcnt,
    int* __restrict__ ready) {
  __shared__ SMem sm;
  const int tid = threadIdx.x;
  const int b = blockIdx.x;
  const int gid = b * NTH + tid;
  const int lane = tid & 63;
  const int wid_g = gid >> 6;
  const int nw = NLANES / 64;
  const int rep = b & (NREP - 1);

  // ---------------- barrier-state init (ws is poisoned 0xAA each launch) ----
  if (b == 0) {
    for (int i = tid; i < NBAR; i += NTH) barcnt[i] = 0;
    __syncthreads();
    if (tid == 0) {
      __threadfence();
      __hip_atomic_store(ready, READY_MAGIC, __ATOMIC_RELEASE, __HIP_MEMORY_SCOPE_AGENT);
    }
    __syncthreads();
  } else {
    if (tid == 0) {
      while (__hip_atomic_load(ready, __ATOMIC_RELAXED, __HIP_MEMORY_SCOPE_AGENT) != READY_MAGIC)
        __builtin_amdgcn_s_sleep(1);
      __threadfence();
    }
    __syncthreads();
  }
  int bar_i = 0;

  // ---------------- phase 0: init (once) ----------------
  for (int i = gid; i < NREP * K_C * DIM; i += NLANES) gsum[i] = 0;
  for (int i = gid; i < K_C * DIM; i += NLANES) cents[i] = init_c[i];
  for (int i = gid; i < NREP * K_C; i += NLANES) gcnt[i] = 0;
  for (int p = wid_g; p < N_PTS; p += nw) {
    float v = embeds[(size_t)p * DIM + lane];
    float s = v * v;
    #pragma unroll
    for (int m = 1; m < 64; m <<= 1) s += __shfl_xor(s, m, 64);
    if (lane == 0) esq[p] = s;
  }
  for (int k = wid_g; k < K_PAD; k += nw) {
    float v = (k < K_C) ? init_c[(size_t)k * DIM + lane] : 0.f;
    float s = v * v;
    #pragma unroll
    for (int m = 1; m < 64; m <<= 1) s += __shfl_xor(s, m, 64);
    if (lane == 0) csq[k] = (k < K_C) ? s : INFINITY;
  }
  grid_barrier(&barcnt[bar_i++]);

  // ---------------- loop-invariant per-block state ----------------
  const int m0 = b * BM;
  const int m_cnt = min(BM, N_PTS - m0);
  const int tx = tid & 15, ty = tid >> 4;

  // stage A once (transposed): As[d][m]  (one-time; conflicts here don't matter)
  #pragma unroll
  for (int l = 0; l < 8; ++l) {
    int e = tid + l * 256;
    int pl = e >> 4, d4 = e & 15;
    int p = m0 + pl;
    float4 v = make_float4(0.f, 0.f, 0.f, 0.f);
    if (p < N_PTS) v = *reinterpret_cast<const float4*>(embeds + (size_t)p * DIM + d4 * 4);
    sm.As[d4 * 4 + 0][pl] = v.x; sm.As[d4 * 4 + 1][pl] = v.y;
    sm.As[d4 * 4 + 2][pl] = v.z; sm.As[d4 * 4 + 3][pl] = v.w;
  }
  // split m-frag: rows ty*4..+3 and 64+ty*4..+3  (conflict-free b128 reads)
  float esq_r[8];
  #pragma unroll
  for (int i = 0; i < 8; ++i) {
    int mi = (i < 4) ? (ty * 4 + i) : (64 + ty * 4 + (i - 4));
    int p = m0 + mi;
    esq_r[i] = (p < N_PTS) ? esq[p] : 0.f;
  }

  const int g_acc = tid >> 6;        // 4 groups of 64 lanes for accumulation

  for (int it = 0; it < N_ITERS; ++it) {
    float best[8]; int bidx[8];
    #pragma unroll
    for (int i = 0; i < 8; ++i) { best[i] = INFINITY; bidx[i] = 0; }

    for (int t = 0; t < NTILE; ++t) {
      const int n0 = t * BN;
      __syncthreads();               // protect previous Bs/blkidx readers
      // stage B tile, lane-major in kl so scalar-write banks = kl%32 (conflict-free)
      #pragma unroll
      for (int l = 0; l < 8; ++l) {
        int e2 = tid + l * 256;
        int kl = e2 & 127, d4 = e2 >> 7;
        int k = n0 + kl;
        float4 v = make_float4(0.f, 0.f, 0.f, 0.f);
        if (k < K_C) v = *reinterpret_cast<const float4*>(cents + (size_t)k * DIM + d4 * 4);
        sm.u.Bs[d4 * 4 + 0][kl] = v.x; sm.u.Bs[d4 * 4 + 1][kl] = v.y;
        sm.u.Bs[d4 * 4 + 2][kl] = v.z; sm.u.Bs[d4 * 4 + 3][kl] = v.w;
      }
      __syncthreads();

      float acc[8][8];
      #pragma unroll
      for (int i = 0; i < 8; ++i)
        #pragma unroll
        for (int j = 0; j < 8; ++j) acc[i][j] = 0.f;

      #pragma unroll 8
      for (int d = 0; d < DIM; ++d) {
        float4 a0 = *reinterpret_cast<const float4*>(&sm.As[d][ty * 4]);
        float4 a1 = *reinterpret_cast<const float4*>(&sm.As[d][64 + ty * 4]);
        float4 b0 = *reinterpret_cast<const float4*>(&sm.u.Bs[d][tx * 4]);
        float4 b1 = *reinterpret_cast<const float4*>(&sm.u.Bs[d][64 + tx * 4]);
        float av[8] = {a0.x, a0.y, a0.z, a0.w, a1.x, a1.y, a1.z, a1.w};
        float bv[8] = {b0.x, b0.y, b0.z, b0.w, b1.x, b1.y, b1.z, b1.w};
        #pragma unroll
        for (int i = 0; i < 8; ++i)
          #pragma unroll
          for (int j = 0; j < 8; ++j)
            acc[i][j] = fmaf(av[i], bv[j], acc[i][j]);
      }

      float4 c0 = *reinterpret_cast<const float4*>(&csq[n0 + tx * 4]);
      float4 c1 = *reinterpret_cast<const float4*>(&csq[n0 + 64 + tx * 4]);
      float cv[8] = {c0.x, c0.y, c0.z, c0.w, c1.x, c1.y, c1.z, c1.w};
      #pragma unroll
      for (int j = 0; j < 8; ++j) {
        int n = n0 + ((j < 4) ? (tx * 4 + j) : (64 + tx * 4 + (j - 4)));
        #pragma unroll
        for (int i = 0; i < 8; ++i) {
          float dd = (esq_r[i] - 2.0f * acc[i][j]) + cv[j];
          if (dd < best[i]) { best[i] = dd; bidx[i] = n; }
        }
      }
    }

    // cross-lane argmin over 16 tx lanes (registers only)
    #pragma unroll
    for (int i = 0; i < 8; ++i) {
      float v = best[i]; int bi = bidx[i];
      #pragma unroll
      for (int s = 1; s < 16; s <<= 1) {
        float ov = __shfl_xor(v, s, 64);
        int   oi = __shfl_xor(bi, s, 64);
        if (ov < v || (ov == v && oi < bi)) { v = ov; bi = oi; }
      }
      best[i] = v; bidx[i] = bi;
    }

    __syncthreads();                 // all Bs reads done before aliasing with blkidx
    if (tx == 0) {
      #pragma unroll
      for (int i = 0; i < 8; ++i) {
        int pl = (i < 4) ? (ty * 4 + i) : (64 + ty * 4 + (i - 4));
        sm.u.blkidx[pl] = bidx[i];
        int p = m0 + pl;
        if (it == N_ITERS - 1 && p < N_PTS) idx[p] = bidx[i];  // only final needed
      }
    }
    __syncthreads();

    // fused accumulation: int64 fixed-point atomics, NREP-replicated targets
    long long* gs = gsum + (size_t)rep * (K_C * DIM);
    int* gc = gcnt + rep * K_C;
    #pragma unroll 4
    for (int pl = g_acc; pl < m_cnt; pl += 4) {
      int k = sm.u.blkidx[pl];
      float v = embeds[(size_t)(m0 + pl) * DIM + lane];
      long long iv = __float2ll_rn(v * FPSCALE);
      atomicAdd((unsigned long long*)&gs[k * DIM + lane], (unsigned long long)iv);
      if (lane == 0) atomicAdd(&gc[k], 1);
    }
    grid_barrier(&barcnt[bar_i++]);

    // update phase: 32000 elems over first 125 blocks (wave-aligned cutoff)
    if (gid < K_C * DIM) {
      int k = gid >> 6;
      long long s = 0;
      #pragma unroll
      for (int r = 0; r < NREP; ++r) {
        s += gsum[(size_t)r * (K_C * DIM) + gid];
        gsum[(size_t)r * (K_C * DIM) + gid] = 0;   // re-zero for next iter
      }
      int c = 0;
      #pragma unroll
      for (int r = 0; r < NREP; ++r) c += gcnt[r * K_C + k];
      float sum_f = (float)((double)s * INV_FPSCALE);
      float nc = sum_f / ((float)c + 1e-6f);   // matches sums / (counts + EPS)
      cents[gid] = nc;
      float sq = nc * nc;
      #pragma unroll
      for (int m = 1; m < 64; m <<= 1) sq += __shfl_xor(sq, m, 64);
      if (lane == 0) {
        csq[k] = sq; cntf[k] = (float)c;
        #pragma unroll
        for (int r = 0; r < NREP; ++r) gcnt[r * K_C + k] = 0;
      }
    }
    grid_barrier(&barcnt[bar_i++]);
  }

  // ---------------- final output ----------------
  const int tot = K_C * DIM + N_PTS + K_C;
  for (int i = gid; i < tot; i += NLANES) {
    float v;
    if (i < K_C * DIM) v = cents[i];
    else if (i < K_C * DIM + N_PTS) v = (float)idx[i - K_C * DIM];
    else v = cntf[i - K_C * DIM - N_PTS];
    out[i] = v;
  }
}

// ---------------------------------------------------------------------------
extern "C" void kernel_launch(void* const* d_in, const int* in_sizes, int n_in,
                              void* d_out, int out_size, void* d_ws, size_t ws_size,
                              hipStream_t stream) {
  const float* embeds = (const float*)d_in[0];
  const float* init_c = (const float*)d_in[1];
  float* out = (float*)d_out;

  char* w = (char*)d_ws;
  size_t off = 0;
  auto alloc = [&](size_t bytes) -> void* {
    void* p = w + off;
    off += (bytes + 255) & ~(size_t)255;
    return p;
  };
  float*     cents  = (float*)    alloc((size_t)K_C * DIM * sizeof(float));
  float*     csq    = (float*)    alloc((size_t)K_PAD * sizeof(float));
  float*     esq    = (float*)    alloc((size_t)N_PTS * sizeof(float));
  int*       idx    = (int*)      alloc((size_t)N_PTS * sizeof(int));
  float*     cntf   = (float*)    alloc((size_t)K_C * sizeof(float));
  int*       gcnt   = (int*)      alloc((size_t)NREP * K_C * sizeof(int));
  long long* gsum   = (long long*)alloc((size_t)NREP * K_C * DIM * sizeof(long long));
  int*       barcnt = (int*)      alloc((size_t)NBAR * sizeof(int));
  int*       ready  = (int*)      alloc(256);

  void* args[] = {(void*)&embeds, (void*)&init_c, (void*)&out,
                  (void*)&cents, (void*)&csq, (void*)&esq, (void*)&idx,
                  (void*)&cntf, (void*)&gcnt, (void*)&gsum,
                  (void*)&barcnt, (void*)&ready};
  hipLaunchCooperativeKernel((void*)k_kmeans, dim3(GRIDSZ), dim3(NTH), args, 0, stream);
}